// Round 1
// 1022.214 us; speedup vs baseline: 1.0921x; 1.0921x over previous
//
#include <hip/hip_runtime.h>
#include <cstdint>
#include <cstddef>

#define Bc 2
#define Sc 2048
#define Ec 1024
#define Hc 16
#define Dc 64
#define BSc 4096   // B*S
#define BHc 32     // B*H

typedef __attribute__((ext_vector_type(8))) short bf16x8;
typedef __attribute__((ext_vector_type(4))) float f32x4;

__device__ __forceinline__ uint16_t f2b(float x) {
  union { float f; uint32_t u; } v; v.f = x;
  return (uint16_t)((v.u + 0x7FFFu + ((v.u >> 16) & 1u)) >> 16);
}

// ---------------- prep: fp32 -> bf16 cast ----------------
__global__ void conv_bf16(const float* __restrict__ src, uint16_t* __restrict__ dst, int n) {
  int i = (blockIdx.x * blockDim.x + threadIdx.x) * 4;
  if (i < n) {
    float4 v = *(const float4*)(src + i);
    ushort4 o;
    o.x = f2b(v.x); o.y = f2b(v.y); o.z = f2b(v.z); o.w = f2b(v.w);
    *(ushort4*)(dst + i) = o;
  }
}

// ---------------- prep: W (K x N fp32) -> WT (N x K bf16) ----------------
__global__ void transpose_bf16(const float* __restrict__ src, uint16_t* __restrict__ dst) {
  __shared__ uint16_t tile[32][33];
  int x0 = blockIdx.x * 32, y0 = blockIdx.y * 32;
  int tx = threadIdx.x & 31, ty = threadIdx.x >> 5;  // 256 thr: ty 0..7
#pragma unroll
  for (int i = 0; i < 32; i += 8)
    tile[ty + i][tx] = f2b(src[(size_t)(y0 + ty + i) * 1024 + x0 + tx]);
  __syncthreads();
#pragma unroll
  for (int i = 0; i < 32; i += 8)
    dst[(size_t)(x0 + ty + i) * 1024 + y0 + tx] = tile[tx][ty + i];
}

// ---------------- QKV projection GEMM ----------------
// A: M x K bf16 (M=4096,K=1024), BT: N x K bf16 (N=1024), bias fp32[N]
// mode 0: out[b][h][s][d]   mode 1: out[b][h][d][s]  (vT)
__global__ __launch_bounds__(256) void gemm_proj(
    const uint16_t* __restrict__ A, const uint16_t* __restrict__ BT,
    const float* __restrict__ bias, uint16_t* __restrict__ out, int mode) {
  const int K = 1024;
  __shared__ uint16_t As[128 * 40];
  __shared__ uint16_t Bs[128 * 40];
  int n0 = blockIdx.x * 128, m0 = blockIdx.y * 128;
  int t = threadIdx.x;
  int wave = t >> 6, lane = t & 63;
  int wm = (wave >> 1) * 64, wn = (wave & 1) * 64;
  int quad = lane >> 4, l16 = lane & 15;

  f32x4 acc[4][4];
#pragma unroll
  for (int i = 0; i < 4; i++)
#pragma unroll
    for (int j = 0; j < 4; j++) acc[i][j] = (f32x4)(0.0f);

  int srow = t >> 1, scol = (t & 1) * 16;  // thread loads 32B of a 64B tile-row

  for (int k0 = 0; k0 < K; k0 += 32) {
    const uint16_t* ag = A + (size_t)(m0 + srow) * K + k0 + scol;
    const uint16_t* bg = BT + (size_t)(n0 + srow) * K + k0 + scol;
    uint4 av0 = *(const uint4*)ag;
    uint4 av1 = *(const uint4*)(ag + 8);
    uint4 bv0 = *(const uint4*)bg;
    uint4 bv1 = *(const uint4*)(bg + 8);
    __syncthreads();
    *(uint4*)(As + srow * 40 + scol) = av0;
    *(uint4*)(As + srow * 40 + scol + 8) = av1;
    *(uint4*)(Bs + srow * 40 + scol) = bv0;
    *(uint4*)(Bs + srow * 40 + scol + 8) = bv1;
    __syncthreads();
    bf16x8 af[4], bfr[4];
#pragma unroll
    for (int i = 0; i < 4; i++)
      af[i] = *(const bf16x8*)(As + (wm + i * 16 + l16) * 40 + quad * 8);
#pragma unroll
    for (int j = 0; j < 4; j++)
      bfr[j] = *(const bf16x8*)(Bs + (wn + j * 16 + l16) * 40 + quad * 8);
#pragma unroll
    for (int i = 0; i < 4; i++)
#pragma unroll
      for (int j = 0; j < 4; j++)
        acc[i][j] = __builtin_amdgcn_mfma_f32_16x16x32_bf16(af[i], bfr[j], acc[i][j], 0, 0, 0);
  }
#pragma unroll
  for (int i = 0; i < 4; i++)
#pragma unroll
    for (int j = 0; j < 4; j++) {
      int col = n0 + wn + j * 16 + l16;
      float bval = bias[col];
      int h = col >> 6, d = col & 63;
#pragma unroll
      for (int r = 0; r < 4; r++) {
        int row = m0 + wm + i * 16 + quad * 4 + r;
        int b = row >> 11, s = row & 2047;
        uint16_t hv = f2b(acc[i][j][r] + bval);
        if (mode == 0)
          out[(size_t)((b * Hc + h) * Sc + s) * Dc + d] = hv;
        else
          out[(size_t)((b * Hc + h) * Dc + d) * Sc + s] = hv;
      }
    }
}

// ---------------- output projection GEMM + bias + residual ----------------
__global__ __launch_bounds__(256) void gemm_out(
    const uint16_t* __restrict__ A, const uint16_t* __restrict__ BT,
    const float* __restrict__ bias, const float* __restrict__ resid,
    float* __restrict__ x) {
  const int K = 1024;
  __shared__ uint16_t As[128 * 40];
  __shared__ uint16_t Bs[128 * 40];
  int n0 = blockIdx.x * 128, m0 = blockIdx.y * 128;
  int t = threadIdx.x;
  int wave = t >> 6, lane = t & 63;
  int wm = (wave >> 1) * 64, wn = (wave & 1) * 64;
  int quad = lane >> 4, l16 = lane & 15;

  f32x4 acc[4][4];
#pragma unroll
  for (int i = 0; i < 4; i++)
#pragma unroll
    for (int j = 0; j < 4; j++) acc[i][j] = (f32x4)(0.0f);

  int srow = t >> 1, scol = (t & 1) * 16;
  for (int k0 = 0; k0 < K; k0 += 32) {
    const uint16_t* ag = A + (size_t)(m0 + srow) * K + k0 + scol;
    const uint16_t* bg = BT + (size_t)(n0 + srow) * K + k0 + scol;
    uint4 av0 = *(const uint4*)ag;
    uint4 av1 = *(const uint4*)(ag + 8);
    uint4 bv0 = *(const uint4*)bg;
    uint4 bv1 = *(const uint4*)(bg + 8);
    __syncthreads();
    *(uint4*)(As + srow * 40 + scol) = av0;
    *(uint4*)(As + srow * 40 + scol + 8) = av1;
    *(uint4*)(Bs + srow * 40 + scol) = bv0;
    *(uint4*)(Bs + srow * 40 + scol + 8) = bv1;
    __syncthreads();
    bf16x8 af[4], bfr[4];
#pragma unroll
    for (int i = 0; i < 4; i++)
      af[i] = *(const bf16x8*)(As + (wm + i * 16 + l16) * 40 + quad * 8);
#pragma unroll
    for (int j = 0; j < 4; j++)
      bfr[j] = *(const bf16x8*)(Bs + (wn + j * 16 + l16) * 40 + quad * 8);
#pragma unroll
    for (int i = 0; i < 4; i++)
#pragma unroll
      for (int j = 0; j < 4; j++)
        acc[i][j] = __builtin_amdgcn_mfma_f32_16x16x32_bf16(af[i], bfr[j], acc[i][j], 0, 0, 0);
  }
#pragma unroll
  for (int i = 0; i < 4; i++)
#pragma unroll
    for (int j = 0; j < 4; j++) {
      int col = n0 + wn + j * 16 + l16;
      float bval = bias[col];
#pragma unroll
      for (int r = 0; r < 4; r++) {
        int row = m0 + wm + i * 16 + quad * 4 + r;
        x[(size_t)row * 1024 + col] = acc[i][j][r] + bval + resid[(size_t)row * 1024 + col];
      }
    }
}

// ---------------- fused attention: rowsum pass + (normalize+write attn+PV) pass ----------------
// Swapped-operand QK^T: sacc = mfma(K_frag, Q_frag) so each lane owns one q-row
// (col = l16). Pass 1 accumulates rowsums (per-lane adds + 2 shfl_xor). Pass 2
// recomputes scores (bitwise-identical), writes normalized attn ONCE (float4
// stores), stages P bf16 into LDS (ds_write_b64), and does PV MFMA.
__global__ __launch_bounds__(256) void fused_attn(
    const uint16_t* __restrict__ qh,   // [BH,S,64]
    const uint16_t* __restrict__ kh,   // [BH,S,64]
    const uint16_t* __restrict__ vT,   // [BH,64,S]
    const int* __restrict__ mask,      // [B,S,S] (nonzero -> masked)
    float* __restrict__ attn,          // [BH,S,S] normalized out
    uint16_t* __restrict__ ctx) {      // [B,S,H*64]
  __shared__ uint16_t Qs[64 * 72];
  __shared__ uint16_t Ks[64 * 72];
  __shared__ uint16_t Vs[64 * 72];
  __shared__ uint16_t Ps[64 * 72];
  __shared__ float rinv_s[64];

  int m0 = blockIdx.x * 64;
  int bh = blockIdx.y;
  int b = bh >> 4;
  int t = threadIdx.x;
  int wave = t >> 6, lane = t & 63;
  int quad = lane >> 4, l16 = lane & 15;

  int srow = t >> 2, scol = (t & 3) * 16;  // staging: 64 rows x 64 bf16, 32B/thread

  // stage Q strip once (reused by both passes)
  {
    const uint16_t* qg = qh + (size_t)(bh * Sc + m0 + srow) * Dc + scol;
    uint4 q0 = *(const uint4*)qg;
    uint4 q1 = *(const uint4*)(qg + 8);
    *(uint4*)(Qs + srow * 72 + scol) = q0;
    *(uint4*)(Qs + srow * 72 + scol + 8) = q1;
  }
  __syncthreads();

  int m = m0 + wave * 16 + l16;  // this lane's q-row (swapped layout: col=l16)
  const int* mrow = mask + (size_t)(b * Sc + m) * Sc;

  // Q fragments for this lane's row group: loop-invariant
  bf16x8 qf0 = *(const bf16x8*)(Qs + (wave * 16 + l16) * 72 + quad * 8);
  bf16x8 qf1 = *(const bf16x8*)(Qs + (wave * 16 + l16) * 72 + 32 + quad * 8);

  // ---------------- pass 1: rowsums only ----------------
  float rs = 0.0f;
  for (int k0 = 0; k0 < Sc; k0 += 64) {
    const uint16_t* kg = kh + (size_t)(bh * Sc + k0 + srow) * Dc + scol;
    uint4 kv0 = *(const uint4*)kg;
    uint4 kv1 = *(const uint4*)(kg + 8);
    __syncthreads();
    *(uint4*)(Ks + srow * 72 + scol) = kv0;
    *(uint4*)(Ks + srow * 72 + scol + 8) = kv1;
    __syncthreads();
    // prefetch mask (latency hides under MFMA)
    int4 mv[4];
#pragma unroll
    for (int j = 0; j < 4; j++)
      mv[j] = *(const int4*)(mrow + k0 + j * 16 + quad * 4);
    f32x4 sacc[4];
#pragma unroll
    for (int j = 0; j < 4; j++) sacc[j] = (f32x4)(0.0f);
#pragma unroll
    for (int j = 0; j < 4; j++) {
      bf16x8 kf0 = *(const bf16x8*)(Ks + (j * 16 + l16) * 72 + quad * 8);
      bf16x8 kf1 = *(const bf16x8*)(Ks + (j * 16 + l16) * 72 + 32 + quad * 8);
      sacc[j] = __builtin_amdgcn_mfma_f32_16x16x32_bf16(kf0, qf0, sacc[j], 0, 0, 0);
      sacc[j] = __builtin_amdgcn_mfma_f32_16x16x32_bf16(kf1, qf1, sacc[j], 0, 0, 0);
    }
#pragma unroll
    for (int j = 0; j < 4; j++) {
      rs += mv[j].x ? 0.0f : __expf(sacc[j][0] * 0.125f);
      rs += mv[j].y ? 0.0f : __expf(sacc[j][1] * 0.125f);
      rs += mv[j].z ? 0.0f : __expf(sacc[j][2] * 0.125f);
      rs += mv[j].w ? 0.0f : __expf(sacc[j][3] * 0.125f);
    }
  }
  // reduce over the 4 quads holding the same q-row
  rs += __shfl_xor(rs, 16);
  rs += __shfl_xor(rs, 32);
  if (lane < 16) rinv_s[wave * 16 + l16] = 1.0f / rs;
  __syncthreads();
  float rv = rinv_s[wave * 16 + l16];

  // ---------------- pass 2: normalize + write attn + PV ----------------
  f32x4 cacc[4];
#pragma unroll
  for (int j = 0; j < 4; j++) cacc[j] = (f32x4)(0.0f);

  for (int k0 = 0; k0 < Sc; k0 += 64) {
    const uint16_t* kg = kh + (size_t)(bh * Sc + k0 + srow) * Dc + scol;
    const uint16_t* vg = vT + (size_t)(bh * Dc + srow) * Sc + k0 + scol;
    uint4 kv0 = *(const uint4*)kg;
    uint4 kv1 = *(const uint4*)(kg + 8);
    uint4 vv0 = *(const uint4*)vg;
    uint4 vv1 = *(const uint4*)(vg + 8);
    __syncthreads();
    *(uint4*)(Ks + srow * 72 + scol) = kv0;
    *(uint4*)(Ks + srow * 72 + scol + 8) = kv1;
    *(uint4*)(Vs + srow * 72 + scol) = vv0;
    *(uint4*)(Vs + srow * 72 + scol + 8) = vv1;
    __syncthreads();
    int4 mv[4];
#pragma unroll
    for (int j = 0; j < 4; j++)
      mv[j] = *(const int4*)(mrow + k0 + j * 16 + quad * 4);
    f32x4 sacc[4];
#pragma unroll
    for (int j = 0; j < 4; j++) sacc[j] = (f32x4)(0.0f);
#pragma unroll
    for (int j = 0; j < 4; j++) {
      bf16x8 kf0 = *(const bf16x8*)(Ks + (j * 16 + l16) * 72 + quad * 8);
      bf16x8 kf1 = *(const bf16x8*)(Ks + (j * 16 + l16) * 72 + 32 + quad * 8);
      sacc[j] = __builtin_amdgcn_mfma_f32_16x16x32_bf16(kf0, qf0, sacc[j], 0, 0, 0);
      sacc[j] = __builtin_amdgcn_mfma_f32_16x16x32_bf16(kf1, qf1, sacc[j], 0, 0, 0);
    }
    float* arow = attn + (size_t)(bh * Sc + m) * Sc + k0;
#pragma unroll
    for (int j = 0; j < 4; j++) {
      float p0 = mv[j].x ? 0.0f : __expf(sacc[j][0] * 0.125f) * rv;
      float p1 = mv[j].y ? 0.0f : __expf(sacc[j][1] * 0.125f) * rv;
      float p2 = mv[j].z ? 0.0f : __expf(sacc[j][2] * 0.125f) * rv;
      float p3 = mv[j].w ? 0.0f : __expf(sacc[j][3] * 0.125f) * rv;
      // attn write: lane covers 4 consecutive n -> one dwordx4 store
      *(float4*)(arow + j * 16 + quad * 4) = make_float4(p0, p1, p2, p3);
      // stage normalized bf16 P for PV: Ps[m_local][n_local], 4 elems -> b64
      union { uint16_t u[4]; uint2 v; } pk;
      pk.u[0] = f2b(p0); pk.u[1] = f2b(p1); pk.u[2] = f2b(p2); pk.u[3] = f2b(p3);
      *(uint2*)(Ps + (wave * 16 + l16) * 72 + j * 16 + quad * 4) = pk.v;
    }
    // PV: A = P[m][k] (rows written only by this wave -> no barrier needed;
    // compiler orders the intra-wave ds_write->ds_read), B = V^T[d][k]
    bf16x8 pf0 = *(const bf16x8*)(Ps + (wave * 16 + l16) * 72 + quad * 8);
    bf16x8 pf1 = *(const bf16x8*)(Ps + (wave * 16 + l16) * 72 + 32 + quad * 8);
#pragma unroll
    for (int j = 0; j < 4; j++) {
      bf16x8 vf0 = *(const bf16x8*)(Vs + (j * 16 + l16) * 72 + quad * 8);
      bf16x8 vf1 = *(const bf16x8*)(Vs + (j * 16 + l16) * 72 + 32 + quad * 8);
      cacc[j] = __builtin_amdgcn_mfma_f32_16x16x32_bf16(pf0, vf0, cacc[j], 0, 0, 0);
      cacc[j] = __builtin_amdgcn_mfma_f32_16x16x32_bf16(pf1, vf1, cacc[j], 0, 0, 0);
    }
  }
  // epilogue: ctx write (C-layout: row = quad*4+r within wave's 16 rows, col=l16)
  int h = bh & 15;
#pragma unroll
  for (int j = 0; j < 4; j++) {
    int d = j * 16 + l16;
#pragma unroll
    for (int r = 0; r < 4; r++) {
      int s = m0 + wave * 16 + quad * 4 + r;
      ctx[(size_t)(b * Sc + s) * (Hc * Dc) + h * Dc + d] = f2b(cacc[j][r]);
    }
  }
}

// ---------------- LayerNorm ----------------
__global__ __launch_bounds__(256) void ln_kernel(
    const float* __restrict__ x, const float* __restrict__ gamma,
    const float* __restrict__ beta, float* __restrict__ y) {
  int row = blockIdx.x;
  int t = threadIdx.x;
  const float* xr = x + (size_t)row * 1024;
  float4 v = *(const float4*)(xr + t * 4);
  float s = v.x + v.y + v.z + v.w;
  float s2 = v.x * v.x + v.y * v.y + v.z * v.z + v.w * v.w;
#pragma unroll
  for (int o = 1; o < 64; o <<= 1) {
    s += __shfl_xor(s, o);
    s2 += __shfl_xor(s2, o);
  }
  __shared__ float ss[4], ss2[4];
  int wave = t >> 6, lane = t & 63;
  if (lane == 0) { ss[wave] = s; ss2[wave] = s2; }
  __syncthreads();
  s = ss[0] + ss[1] + ss[2] + ss[3];
  s2 = ss2[0] + ss2[1] + ss2[2] + ss2[3];
  float mu = s * (1.0f / 1024.0f);
  float var = s2 * (1.0f / 1024.0f) - mu * mu;
  float rstd = rsqrtf(var + 1e-5f);
  float4 g = *(const float4*)(gamma + t * 4);
  float4 be = *(const float4*)(beta + t * 4);
  float4 o;
  o.x = (v.x - mu) * rstd * g.x + be.x;
  o.y = (v.y - mu) * rstd * g.y + be.y;
  o.z = (v.z - mu) * rstd * g.z + be.z;
  o.w = (v.w - mu) * rstd * g.w + be.w;
  *(float4*)(y + (size_t)row * 1024 + t * 4) = o;
}

extern "C" void kernel_launch(void* const* d_in, const int* in_sizes, int n_in,
                              void* d_out, int out_size, void* d_ws, size_t ws_size,
                              hipStream_t stream) {
  const float* Q = (const float*)d_in[0];
  const float* K = (const float*)d_in[1];
  const float* V = (const float*)d_in[2];
  const int* mask = (const int*)d_in[3];
  const float* Wq = (const float*)d_in[4];
  const float* bq = (const float*)d_in[5];
  const float* Wk = (const float*)d_in[6];
  const float* bk = (const float*)d_in[7];
  const float* Wv = (const float*)d_in[8];
  const float* bv = (const float*)d_in[9];
  const float* Wo = (const float*)d_in[10];
  const float* bo = (const float*)d_in[11];
  const float* gamma = (const float*)d_in[12];
  const float* beta = (const float*)d_in[13];

  float* y = (float*)d_out;                           // [B,S,E]
  float* attn = (float*)d_out + (size_t)BSc * Ec;     // [B,H,S,S]

  char* ws = (char*)d_ws;
  size_t off = 0;
  auto alloc = [&](size_t bytes) -> void* {
    void* p = ws + off;
    off = (off + bytes + 255) & ~(size_t)255;
    return p;
  };
  uint16_t* Qb  = (uint16_t*)alloc((size_t)BSc * Ec * 2);
  uint16_t* Kb  = (uint16_t*)alloc((size_t)BSc * Ec * 2);
  uint16_t* Vb  = (uint16_t*)alloc((size_t)BSc * Ec * 2);
  uint16_t* WqT = (uint16_t*)alloc((size_t)Ec * Ec * 2);
  uint16_t* WkT = (uint16_t*)alloc((size_t)Ec * Ec * 2);
  uint16_t* WvT = (uint16_t*)alloc((size_t)Ec * Ec * 2);
  uint16_t* WoT = (uint16_t*)alloc((size_t)Ec * Ec * 2);
  uint16_t* qh  = (uint16_t*)alloc((size_t)BHc * Sc * Dc * 2);  // [BH,S,64]
  uint16_t* kh  = (uint16_t*)alloc((size_t)BHc * Sc * Dc * 2);  // [BH,S,64]
  uint16_t* vT  = (uint16_t*)alloc((size_t)BHc * Dc * Sc * 2);  // [BH,64,S]
  uint16_t* ctx = (uint16_t*)alloc((size_t)BSc * Ec * 2);       // [B,S,1024]
  float* xres   = (float*)alloc((size_t)BSc * Ec * 4);

  const int n_qkv = BSc * Ec;  // 4,194,304

  // 1) casts
  conv_bf16<<<n_qkv / 1024, 256, 0, stream>>>(Q, Qb, n_qkv);
  conv_bf16<<<n_qkv / 1024, 256, 0, stream>>>(K, Kb, n_qkv);
  conv_bf16<<<n_qkv / 1024, 256, 0, stream>>>(V, Vb, n_qkv);
  // 2) weight transposes
  dim3 tg(32, 32);
  transpose_bf16<<<tg, 256, 0, stream>>>(Wq, WqT);
  transpose_bf16<<<tg, 256, 0, stream>>>(Wk, WkT);
  transpose_bf16<<<tg, 256, 0, stream>>>(Wv, WvT);
  transpose_bf16<<<tg, 256, 0, stream>>>(Wo, WoT);
  // 3) QKV projections
  dim3 pg(Ec / 128, BSc / 128);  // (8, 32)
  gemm_proj<<<pg, 256, 0, stream>>>(Qb, WqT, bq, qh, 0);
  gemm_proj<<<pg, 256, 0, stream>>>(Kb, WkT, bk, kh, 0);
  gemm_proj<<<pg, 256, 0, stream>>>(Vb, WvT, bv, vT, 1);
  // 4) fused attention: rowsum pass + normalize/write/PV pass
  dim3 fg(Sc / 64, BHc);  // (32, 32)
  fused_attn<<<fg, 256, 0, stream>>>(qh, kh, vT, mask, attn, ctx);
  // 5) out projection + residual
  gemm_out<<<pg, 256, 0, stream>>>(ctx, WoT, bo, Q, xres);
  // 6) LayerNorm
  ln_kernel<<<BSc, 256, 0, stream>>>(xres, gamma, beta, y);
}